// Round 18
// baseline (156.392 us; speedup 1.0000x reference)
//
#include <hip/hip_runtime.h>
#include <cmath>

// SSIM + L1 image similarity loss, MI355X (gfx950).
// es, ta: fp32 [16,3,512,512]. Output: out[0]=l1_loss, out[1]=ssim_loss.
//
// R18 = R17 (TILE_H=48, 4-channel u/v rotation, packed v2f) with the spill
// cause fixed: R17's staging arrays se[17]/st_[17] held 34 VGPRs across the
// whole load phase -> 48 acc + 34 + temps > cap 128 -> 253MB scratch.
// Fix: CHUNKED staging -- 3 chunks of <=6 iterations (12 staging regs max),
// each chunk = issue-6-clamped-loads -> write-6-with-mask. ~3 HBM round
// trips per block (vs R15's fixed 12+ serialized; vs R17's 1) -- negligible.
// Live ~= 48 acc + 12 stage + ~25 temps ~= 85 < 128 -> no spill expected.
// Payoff of 48-tall tile: redundancy 2.25->1.83x, main-loop issues -12%/px,
// LDS reads -18%/px.

typedef float v2f __attribute__((ext_vector_type(2)));

constexpr int TILE_W = 64;
constexpr int TILE_H = 48;
constexpr int HALO = 5;
constexpr int WIN  = 11;
constexpr int ROWS_PER_WAVE = TILE_H / 4;            // 12
constexpr int STREAM_ROWS = ROWS_PER_WAVE + WIN - 1; // 22
constexpr int LH   = TILE_H + 2 * HALO;  // 58 staged rows
constexpr int LW   = TILE_W + 2 * HALO;  // 74 staged cols
constexpr int LSTR = 76;                 // LDS row stride (v2f units)
constexpr int IMG  = 512;
constexpr int TOTAL = LH * LW;           // 4292 staged elements
constexpr int NIT = (TOTAL + 255) / 256; // 17 stage iterations
constexpr int CHUNK = 6;                 // stage iterations per chunk
constexpr float C1C = 0.01f * 0.01f;
constexpr float C2C = 0.03f * 0.03f;

struct Wnd { float g[WIN]; };

__global__ __launch_bounds__(256, 2) void ssim_main(
    const float* __restrict__ es, const float* __restrict__ ta,
    float2* __restrict__ partials, Wnd w)
{
    __shared__ v2f sS[LH * LSTR];
    __shared__ float2 red[4];

    const int tid = threadIdx.x;
    const int tx0 = blockIdx.x * TILE_W;
    const int ty0 = blockIdx.y * TILE_H;
    const int img = blockIdx.z;
    const float* pe = es + (size_t)img * (IMG * IMG);
    const float* pt = ta + (size_t)img * (IMG * IMG);

    // ---- staging: 3 chunks of {issue 6 clamped loads -> masked writes} ----
    #pragma unroll
    for (int ch = 0; ch < 3; ++ch) {
        float se[CHUNK], st_[CHUNK];
        #pragma unroll
        for (int j = 0; j < CHUNK; ++j) {
            int it = ch * CHUNK + j;
            if (it < NIT) {
                int i = it * 256 + tid;
                int r = i / LW, c = i - r * LW;
                int gy = ty0 - HALO + r;
                int gx = tx0 - HALO + c;
                int cy = min(max(gy, 0), IMG - 1);
                int cx = min(max(gx, 0), IMG - 1);
                int off = cy * IMG + cx;
                if (i < TOTAL) {             // divergent only at it==16
                    se[j]  = pe[off];
                    st_[j] = pt[off];
                }
            }
        }
        #pragma unroll
        for (int j = 0; j < CHUNK; ++j) {
            int it = ch * CHUNK + j;
            if (it < NIT) {
                int i = it * 256 + tid;
                if (i < TOTAL) {
                    int r = i / LW, c = i - r * LW;
                    int gy = ty0 - HALO + r;
                    int gx = tx0 - HALO + c;
                    bool valid = ((unsigned)gy < (unsigned)IMG) &&
                                 ((unsigned)gx < (unsigned)IMG);
                    float m = valid ? 1.f : 0.f;
                    float e = se[j] * m, t = st_[j] * m;
                    sS[r * LSTR + c] = (v2f){e + t, e - t};   // (u, v)
                }
            }
        }
    }
    __syncthreads();

    const int wv = tid >> 6;   // wave id 0..3 -> 12-row segment
    const int ln = tid & 63;   // lane -> column
    const int rbase = wv * ROWS_PER_WAVE;
    const v2f* rp = &sS[rbase * LSTR + ln];

    v2f am[ROWS_PER_WAVE];     // (mu_u, mu_v) accumulators
    v2f aq[ROWS_PER_WAVE];     // (E[u^2], E[v^2]) accumulators
    #pragma unroll
    for (int o = 0; o < ROWS_PER_WAVE; ++o) {
        am[o] = (v2f){0.f, 0.f}; aq[o] = (v2f){0.f, 0.f};
    }

    #pragma unroll
    for (int rr = 0; rr < STREAM_ROWS; ++rr) {
        // horizontal 11-tap of {(u,v), (u^2,v^2)} for streamed row rr
        v2f hm = {0.f, 0.f};
        v2f hq = {0.f, 0.f};
        #pragma unroll
        for (int k = 0; k < WIN; ++k) {
            v2f uv = rp[rr * LSTR + k];     // ds_read_b64, imm offset
            float gk = w.g[k];
            v2f g2 = {gk, gk};
            v2f gu = g2 * uv;               // v_pk_mul_f32
            hm += gu;                       // v_pk_add_f32
            hq += gu * uv;                  // v_pk_fma_f32
        }

        // vertical scatter: streamed row rr feeds output rows rr-10..rr
        #pragma unroll
        for (int k = 0; k < WIN; ++k) {
            int o = rr - k;
            if (o >= 0 && o < ROWS_PER_WAVE) {
                float gk = w.g[k];
                v2f g2 = {gk, gk};
                am[o] += g2 * hm;           // v_pk_fma_f32
                aq[o] += g2 * hq;           // v_pk_fma_f32
            }
        }
    }

    // ---- epilogue: ssim per pixel + L1, then reduce ----
    float ssim_s = 0.f, l1_s = 0.f;
    #pragma unroll
    for (int o = 0; o < ROWS_PER_WAVE; ++o) {
        if (ty0 + rbase + o < IMG) {       // skip padded rows (last stripe)
            float mu_u = am[o].x, mu_v = am[o].y;
            float mu_u2 = mu_u * mu_u, mu_v2 = mu_v * mu_v;
            float var_u = aq[o].x - mu_u2;
            float var_v = aq[o].y - mu_v2;
            float m12_2 = (mu_u2 - mu_v2) * 0.5f;   // 2*mu1*mu2
            float msum  = (mu_u2 + mu_v2) * 0.5f;   // mu1^2+mu2^2
            float cov2  = (var_u - var_v) * 0.5f;   // 2*sigma12
            float vsum  = (var_u + var_v) * 0.5f;   // sigma1^2+sigma2^2
            float num = (m12_2 + C1C) * (cov2 + C2C);
            float den = (msum + C1C) * (vsum + C2C);
            ssim_s += num * __builtin_amdgcn_rcpf(den);

            v2f c = rp[(o + HALO) * LSTR + HALO];   // center (u,v)
            l1_s += fabsf(c.y);                     // |e-t| = |v|
        }
    }

    // ---- block reduce: wave shfl -> LDS[4] -> thread 0 stores partial ----
    #pragma unroll
    for (int off = 32; off >= 1; off >>= 1) {
        ssim_s += __shfl_xor(ssim_s, off, 64);
        l1_s   += __shfl_xor(l1_s, off, 64);
    }
    if (ln == 0) red[wv] = make_float2(ssim_s, l1_s);
    __syncthreads();
    if (tid == 0) {
        float2 r0 = red[0], r1 = red[1], r2 = red[2], r3 = red[3];
        float2 p = make_float2(r0.x + r1.x + r2.x + r3.x,
                               r0.y + r1.y + r2.y + r3.y);
        int bid = (blockIdx.z * gridDim.y + blockIdx.y) * gridDim.x + blockIdx.x;
        partials[bid] = p;
    }
}

__global__ __launch_bounds__(256) void ssim_reduce(
    const float2* __restrict__ partials, int n, float* __restrict__ out)
{
    __shared__ float2 red[4];
    const int tid = threadIdx.x;
    float ssim_s = 0.f, l1_s = 0.f;
    for (int i = tid; i < n; i += 256) {
        float2 p = partials[i];
        ssim_s += p.x;
        l1_s   += p.y;
    }
    #pragma unroll
    for (int off = 32; off >= 1; off >>= 1) {
        ssim_s += __shfl_xor(ssim_s, off, 64);
        l1_s   += __shfl_xor(l1_s, off, 64);
    }
    if ((tid & 63) == 0) red[tid >> 6] = make_float2(ssim_s, l1_s);
    __syncthreads();
    if (tid == 0) {
        float s = red[0].x + red[1].x + red[2].x + red[3].x;
        float l = red[0].y + red[1].y + red[2].y + red[3].y;
        const float N = 16.f * 3.f * 512.f * 512.f;
        out[0] = 0.15f * (l / N);
        out[1] = 0.85f * 0.5f * (1.f - s / N);
    }
}

extern "C" void kernel_launch(void* const* d_in, const int* in_sizes, int n_in,
                              void* d_out, int out_size, void* d_ws, size_t ws_size,
                              hipStream_t stream)
{
    const float* es = (const float*)d_in[0];
    const float* ta = (const float*)d_in[1];
    float* out = (float*)d_out;
    float2* partials = (float2*)d_ws;

    Wnd w;
    double gd[WIN], sum = 0.0;
    for (int i = 0; i < WIN; ++i) {
        double x = (double)(i - WIN / 2);
        gd[i] = std::exp(-(x * x) / (2.0 * 1.5 * 1.5));
        sum += gd[i];
    }
    for (int i = 0; i < WIN; ++i) w.g[i] = (float)(gd[i] / sum);

    const int nimg = in_sizes[0] / (IMG * IMG);  // 16*3 = 48
    dim3 grid(IMG / TILE_W, (IMG + TILE_H - 1) / TILE_H, nimg);  // 8 x 11 x 48
    const int nblocks = grid.x * grid.y * grid.z;                // 4224
    ssim_main<<<grid, 256, 0, stream>>>(es, ta, partials, w);
    ssim_reduce<<<1, 256, 0, stream>>>(partials, nblocks, out);
}

// Round 19
// 78.222 us; speedup vs baseline: 1.9993x; 1.9993x over previous
//
#include <hip/hip_runtime.h>
#include <cmath>

// SSIM + L1 image similarity loss, MI355X (gfx950).
// es, ta: fp32 [16,3,512,512]. Output: out[0]=l1_loss, out[1]=ssim_loss.
//
// R19 = R16 (78.4us best: 64x32 tile, u/v rotation, packed v2f, batched
// staging, VGPR 40 no-spill) with main-loop LDS issues halved:
//  - lane parity trick: LSTR=76 even -> (ln - (ln&1)) is 16B-aligned; read
//    12 taps as 6x ds_read_b128 (was 11x ds_read_b64). Lane pairs broadcast
//    the same addresses (conflict-free).
//  - per-thread pre-shifted 12-tap weight table ws = p?{0,g}:{g,0} keeps
//    both parities exact (0*x adds exactly 0; order preserved -> absmax 0).
//  - L1 center tap folded into the stream loop (rows 5..12, tap 5+p already
//    in registers) -- epilogue center reads deleted.
// Geometry/staging/scatter/tail byte-identical to R16. R17/R18 lesson:
// TILE_H=48 under cap 128 always spills (~2 rows of in-flight ds_reads +
// 48 accs > 128); geometry stays 64x32.

typedef float v2f __attribute__((ext_vector_type(2)));
typedef float v4f __attribute__((ext_vector_type(4)));

constexpr int TILE_W = 64;
constexpr int TILE_H = 32;
constexpr int HALO = 5;
constexpr int WIN  = 11;
constexpr int ROWS_PER_WAVE = TILE_H / 4;            // 8
constexpr int STREAM_ROWS = ROWS_PER_WAVE + WIN - 1; // 18
constexpr int LH   = TILE_H + 2 * HALO;  // 42 staged rows
constexpr int LW   = TILE_W + 2 * HALO;  // 74 staged cols
constexpr int LSTR = 76;                 // LDS row stride (v2f units), even
constexpr int IMG  = 512;
constexpr int TOTAL = LH * LW;           // 3108 staged elements
constexpr int NIT = (TOTAL + 255) / 256; // 13 stage iterations
constexpr float C1C = 0.01f * 0.01f;
constexpr float C2C = 0.03f * 0.03f;

struct Wnd { float g[WIN]; };

__global__ __launch_bounds__(256, 2) void ssim_main(
    const float* __restrict__ es, const float* __restrict__ ta,
    float2* __restrict__ partials, Wnd w)
{
    __shared__ v4f sS4[LH * LSTR / 2];   // 16B-aligned backing store
    __shared__ float2 red[4];
    v2f* sS = (v2f*)sS4;

    const int tid = threadIdx.x;
    const int tx0 = blockIdx.x * TILE_W;
    const int ty0 = blockIdx.y * TILE_H;
    const int img = blockIdx.z;
    const float* pe = es + (size_t)img * (IMG * IMG);
    const float* pt = ta + (size_t)img * (IMG * IMG);

    // ---- stage, phase A: issue all loads (clamped addr, no branches) ----
    float se[NIT], st_[NIT];
    #pragma unroll
    for (int it = 0; it < NIT; ++it) {
        int i = it * 256 + tid;
        int r = i / LW, c = i - r * LW;
        int gy = ty0 - HALO + r;
        int gx = tx0 - HALO + c;
        int cy = min(max(gy, 0), IMG - 1);
        int cx = min(max(gx, 0), IMG - 1);
        int off = cy * IMG + cx;
        if (i < TOTAL) {                 // divergent only at it==12
            se[it]  = pe[off];
            st_[it] = pt[off];
        }
    }

    // ---- stage, phase B: zero-pad select + (u,v) transform + LDS write ----
    #pragma unroll
    for (int it = 0; it < NIT; ++it) {
        int i = it * 256 + tid;
        if (i < TOTAL) {
            int r = i / LW, c = i - r * LW;
            int gy = ty0 - HALO + r;
            int gx = tx0 - HALO + c;
            bool valid = ((unsigned)gy < (unsigned)IMG) &&
                         ((unsigned)gx < (unsigned)IMG);
            float m = valid ? 1.f : 0.f;
            float e = se[it] * m, t = st_[it] * m;
            sS[r * LSTR + c] = (v2f){e + t, e - t};   // (u, v)
        }
    }
    __syncthreads();

    const int wv = tid >> 6;   // wave id 0..3 -> 8-row segment
    const int ln = tid & 63;   // lane -> column
    const int p  = ln & 1;     // parity: b128 alignment select
    const int rbase = wv * ROWS_PER_WAVE;

    // pre-shifted 12-tap weights: p==0 -> {g0..g10, 0}; p==1 -> {0, g0..g10}
    float ws[12];
    #pragma unroll
    for (int j = 0; j < 12; ++j) {
        float a = (j < WIN) ? w.g[j] : 0.f;
        float b = (j > 0)   ? w.g[j - 1] : 0.f;
        ws[j] = p ? b : a;
    }

    // aligned v4f base: v2f index rbase*LSTR + (ln - p) is even
    const v4f* rp4 = (const v4f*)&sS[rbase * LSTR + (ln - p)];

    v2f am[ROWS_PER_WAVE];     // (mu_u, mu_v) accumulators
    v2f aq[ROWS_PER_WAVE];     // (E[u^2], E[v^2]) accumulators
    #pragma unroll
    for (int o = 0; o < ROWS_PER_WAVE; ++o) {
        am[o] = (v2f){0.f, 0.f}; aq[o] = (v2f){0.f, 0.f};
    }

    float ssim_s = 0.f, l1_s = 0.f;

    #pragma unroll
    for (int rr = 0; rr < STREAM_ROWS; ++rr) {
        // 6x ds_read_b128: 12 taps (u,v) for streamed row rr
        const v4f* qp = rp4 + rr * (LSTR / 2);
        v4f q0 = qp[0], q1 = qp[1], q2 = qp[2],
            q3 = qp[3], q4 = qp[4], q5 = qp[5];

        v2f hm = {0.f, 0.f};
        v2f hq = {0.f, 0.f};
        {
            v2f uv, gu, g2;
            #define TAP(J, LO, HI)                                   \
                uv = (v2f){LO, HI};                                  \
                g2 = (v2f){ws[J], ws[J]};                            \
                gu = g2 * uv;                                        \
                hm += gu;                                            \
                hq += gu * uv;
            TAP(0,  q0.x, q0.y)  TAP(1,  q0.z, q0.w)
            TAP(2,  q1.x, q1.y)  TAP(3,  q1.z, q1.w)
            TAP(4,  q2.x, q2.y)  TAP(5,  q2.z, q2.w)
            TAP(6,  q3.x, q3.y)  TAP(7,  q3.z, q3.w)
            TAP(8,  q4.x, q4.y)  TAP(9,  q4.z, q4.w)
            TAP(10, q5.x, q5.y)  TAP(11, q5.z, q5.w)
            #undef TAP
        }

        // L1: center pixel of output row rr-5 is tap 5+p (already loaded)
        if (rr >= HALO && rr < HALO + ROWS_PER_WAVE) {
            float vcen = p ? q3.y : q2.w;    // tap6.v : tap5.v
            l1_s += fabsf(vcen);
        }

        // vertical scatter: streamed row rr feeds output rows rr-10..rr
        #pragma unroll
        for (int k = 0; k < WIN; ++k) {
            int o = rr - k;
            if (o >= 0 && o < ROWS_PER_WAVE) {
                float gk = w.g[k];
                v2f g2 = {gk, gk};
                am[o] += g2 * hm;           // v_pk_fma_f32
                aq[o] += g2 * hq;           // v_pk_fma_f32
            }
        }
    }

    // ---- epilogue: ssim per pixel, then reduce ----
    #pragma unroll
    for (int o = 0; o < ROWS_PER_WAVE; ++o) {
        float mu_u = am[o].x, mu_v = am[o].y;
        float mu_u2 = mu_u * mu_u, mu_v2 = mu_v * mu_v;
        float var_u = aq[o].x - mu_u2;
        float var_v = aq[o].y - mu_v2;
        float m12_2 = (mu_u2 - mu_v2) * 0.5f;   // 2*mu1*mu2
        float msum  = (mu_u2 + mu_v2) * 0.5f;   // mu1^2+mu2^2
        float cov2  = (var_u - var_v) * 0.5f;   // 2*sigma12
        float vsum  = (var_u + var_v) * 0.5f;   // sigma1^2+sigma2^2
        float num = (m12_2 + C1C) * (cov2 + C2C);
        float den = (msum + C1C) * (vsum + C2C);
        ssim_s += num * __builtin_amdgcn_rcpf(den);
    }

    // ---- block reduce: wave shfl -> LDS[4] -> thread 0 stores partial ----
    #pragma unroll
    for (int off = 32; off >= 1; off >>= 1) {
        ssim_s += __shfl_xor(ssim_s, off, 64);
        l1_s   += __shfl_xor(l1_s, off, 64);
    }
    if (ln == 0) red[wv] = make_float2(ssim_s, l1_s);
    __syncthreads();
    if (tid == 0) {
        float2 r0 = red[0], r1 = red[1], r2 = red[2], r3 = red[3];
        float2 pq = make_float2(r0.x + r1.x + r2.x + r3.x,
                                r0.y + r1.y + r2.y + r3.y);
        int bid = (blockIdx.z * gridDim.y + blockIdx.y) * gridDim.x + blockIdx.x;
        partials[bid] = pq;
    }
}

__global__ __launch_bounds__(256) void ssim_reduce(
    const float2* __restrict__ partials, int n, float* __restrict__ out)
{
    __shared__ float2 red[4];
    const int tid = threadIdx.x;
    float ssim_s = 0.f, l1_s = 0.f;
    for (int i = tid; i < n; i += 256) {
        float2 p = partials[i];
        ssim_s += p.x;
        l1_s   += p.y;
    }
    #pragma unroll
    for (int off = 32; off >= 1; off >>= 1) {
        ssim_s += __shfl_xor(ssim_s, off, 64);
        l1_s   += __shfl_xor(l1_s, off, 64);
    }
    if ((tid & 63) == 0) red[tid >> 6] = make_float2(ssim_s, l1_s);
    __syncthreads();
    if (tid == 0) {
        float s = red[0].x + red[1].x + red[2].x + red[3].x;
        float l = red[0].y + red[1].y + red[2].y + red[3].y;
        const float N = 16.f * 3.f * 512.f * 512.f;
        out[0] = 0.15f * (l / N);
        out[1] = 0.85f * 0.5f * (1.f - s / N);
    }
}

extern "C" void kernel_launch(void* const* d_in, const int* in_sizes, int n_in,
                              void* d_out, int out_size, void* d_ws, size_t ws_size,
                              hipStream_t stream)
{
    const float* es = (const float*)d_in[0];
    const float* ta = (const float*)d_in[1];
    float* out = (float*)d_out;
    float2* partials = (float2*)d_ws;

    Wnd w;
    double gd[WIN], sum = 0.0;
    for (int i = 0; i < WIN; ++i) {
        double x = (double)(i - WIN / 2);
        gd[i] = std::exp(-(x * x) / (2.0 * 1.5 * 1.5));
        sum += gd[i];
    }
    for (int i = 0; i < WIN; ++i) w.g[i] = (float)(gd[i] / sum);

    const int nimg = in_sizes[0] / (IMG * IMG);  // 16*3 = 48
    dim3 grid(IMG / TILE_W, IMG / TILE_H, nimg); // 8 x 16 x 48 = 6144 blocks
    const int nblocks = grid.x * grid.y * grid.z;
    ssim_main<<<grid, 256, 0, stream>>>(es, ta, partials, w);
    ssim_reduce<<<1, 256, 0, stream>>>(partials, nblocks, out);
}